// Round 16
// baseline (39.410 us; speedup 1.0000x reference)
//
#include <hip/hip_runtime.h>
#include <hip/hip_fp16.h>

#define CROP_H 14
#define CROP_W 14
#define CROP_HW 196
#define CROP_HWQ 49          // quad units per box
#define IMG_H 100
#define IMG_W 100
#define PLANE 10000
#define NCH 256
#define NBOX 512
#define NIMG 8

// ---------------- fused single kernel: one block per (b, channel-QUAD) ----------
// Two half2 LDS arrays (c0c1 / c2c3), each 4 B/slot -> conflict-free banking.
// Each 4-tap position's geometry serves FOUR channels' outputs.
__global__ __launch_bounds__(512, 4) void crop_resize_fused(
    const float* __restrict__ image,    // (8, 256, 100, 100)
    const float* __restrict__ boxes,    // (512, 4)
    const int*   __restrict__ box_ind,  // (512,)
    float* __restrict__ out)            // (512, 256, 14, 14)
{
    __shared__ __half2 s_a[PLANE];      // 40000 B: {c0[x], c1[x]}
    __shared__ __half2 s_b[PLANE];      // 40000 B: {c2[x], c3[x]}
    __shared__ float4  s_bgeo[NBOX];    // {ybase, ystep, xbase, xstep} per slot
    __shared__ int     s_perm[NBOX];    // bucket slot -> box id n
    __shared__ int     s_eqw[8];        // per-wave bucket-membership counts

    const int blk  = blockIdx.x;
    const int b    = blk >> 6;          // image 0..7
    const int cq   = blk & 63;          // channel quad 0..63
    const int c0   = cq * 4;
    const int t    = threadIdx.x;
    const int lane = t & 63;
    const int wv   = t >> 6;            // 0..7

    // ---- phase 1a: membership ballot (t covers all 512 boxes) ----
    const int bn_t = box_ind[t];
    const bool mine = (bn_t == b);
    const unsigned long long eq = __ballot(mine);
    if (lane == 0) s_eqw[wv] = __popcll(eq);
    const int pre = __popcll(eq & ((lane == 0) ? 0ull : ((1ull << lane) - 1ull)));

    // ---- phase 2: stage four planes into two channel-pair half2 arrays ----
    const float* __restrict__ p0 = image + ((size_t)(b * NCH + c0)) * PLANE;
    const float4* __restrict__ p0g = reinterpret_cast<const float4*>(p0);
    const float4* __restrict__ p1g = reinterpret_cast<const float4*>(p0 + PLANE);
    const float4* __restrict__ p2g = reinterpret_cast<const float4*>(p0 + 2 * PLANE);
    const float4* __restrict__ p3g = reinterpret_cast<const float4*>(p0 + 3 * PLANE);

    for (int i = t; i < PLANE / 4; i += 512) {
        const float4 f0 = p0g[i];
        const float4 f1 = p1g[i];
        const float4 f2 = p2g[i];
        const float4 f3 = p3g[i];
        const int base = 4 * i;
        s_a[base + 0] = __floats2half2_rn(f0.x, f1.x);
        s_a[base + 1] = __floats2half2_rn(f0.y, f1.y);
        s_a[base + 2] = __floats2half2_rn(f0.z, f1.z);
        s_a[base + 3] = __floats2half2_rn(f0.w, f1.w);
        s_b[base + 0] = __floats2half2_rn(f2.x, f3.x);
        s_b[base + 1] = __floats2half2_rn(f2.y, f3.y);
        s_b[base + 2] = __floats2half2_rn(f2.z, f3.z);
        s_b[base + 3] = __floats2half2_rn(f2.w, f3.w);
    }
    __syncthreads();

    // ---- phase 1b: build perm + per-box geometry scalars ----
    int basecnt = 0, nb = 0;
    #pragma unroll
    for (int i = 0; i < 8; ++i) {
        const int cwv = s_eqw[i];
        if (i < wv) basecnt += cwv;
        nb += cwv;
    }
    if (mine) {
        const int r = basecnt + pre;
        s_perm[r] = t;
        const float4 bx = reinterpret_cast<const float4*>(boxes)[t];
        float4 g;
        g.x = bx.x * (float)(IMG_H - 1);                                  // ybase
        g.y = (bx.z - bx.x) * (float)(IMG_H - 1) / (float)(CROP_H - 1);   // ystep
        g.z = bx.y * (float)(IMG_W - 1);                                  // xbase
        g.w = (bx.w - bx.y) * (float)(IMG_W - 1) / (float)(CROP_W - 1);   // xstep
        s_bgeo[r] = g;
    }
    __syncthreads();

    const int totalq = nb * CROP_HWQ;
    float* __restrict__ outc = out + (size_t)c0 * CROP_HW;

    // ---- phase 3: pure LDS+VALU+store hot loop ----
    for (int q = t; q < totalq; q += 512) {
        const int bl = q / CROP_HWQ;            // magic-mul
        const int j  = q - bl * CROP_HWQ;       // quad index 0..48
        const int n  = s_perm[bl];
        const float4 g = s_bgeo[bl];

        float v0[4], v1[4], v2[4], v3[4];
        #pragma unroll
        for (int k = 0; k < 4; ++k) {
            const int hw = j * 4 + k;
            const int h  = hw / CROP_W;         // magic-mul
            const int w  = hw - h * CROP_W;

            const float in_y = g.x + (float)h * g.y;
            const float in_x = g.z + (float)w * g.w;

            const bool valid = (in_y >= 0.0f) & (in_y <= (float)(IMG_H - 1)) &
                               (in_x >= 0.0f) & (in_x <= (float)(IMG_W - 1));

            const float yc = fminf(fmaxf(in_y, 0.0f), (float)(IMG_H - 1));
            const float xc = fminf(fmaxf(in_x, 0.0f), (float)(IMG_W - 1));

            const float y0f = floorf(yc);
            const float x0f = floorf(xc);
            const float ly = yc - y0f;
            const float lx = xc - x0f;

            const int y0  = (int)y0f;
            const int x0  = (int)x0f;
            const int dx  = min(x0 + 1, IMG_W - 1) - x0;   // 0/1
            const int dyo = (min(y0 + 1, IMG_H - 1) - y0) * IMG_W;

            const int o = y0 * IMG_W + x0;
            const float wm = valid ? 1.0f : 0.0f;

            // array a: channels c0,c1
            {
                const __half2 tl2 = s_a[o];
                const __half2 tr2 = s_a[o + dx];
                const __half2 bl2 = s_a[o + dyo];
                const __half2 br2 = s_a[o + dyo + dx];
                const float tl0 = __low2float(tl2),  tl1 = __high2float(tl2);
                const float tr0 = __low2float(tr2),  tr1 = __high2float(tr2);
                const float bl0 = __low2float(bl2),  bl1 = __high2float(bl2);
                const float br0 = __low2float(br2),  br1 = __high2float(br2);
                const float top0 = tl0 + (tr0 - tl0) * lx;
                const float bot0 = bl0 + (br0 - bl0) * lx;
                const float top1 = tl1 + (tr1 - tl1) * lx;
                const float bot1 = bl1 + (br1 - bl1) * lx;
                v0[k] = (top0 + (bot0 - top0) * ly) * wm;
                v1[k] = (top1 + (bot1 - top1) * ly) * wm;
            }
            // array b: channels c2,c3
            {
                const __half2 tl2 = s_b[o];
                const __half2 tr2 = s_b[o + dx];
                const __half2 bl2 = s_b[o + dyo];
                const __half2 br2 = s_b[o + dyo + dx];
                const float tl0 = __low2float(tl2),  tl1 = __high2float(tl2);
                const float tr0 = __low2float(tr2),  tr1 = __high2float(tr2);
                const float bl0 = __low2float(bl2),  bl1 = __high2float(bl2);
                const float br0 = __low2float(br2),  br1 = __high2float(br2);
                const float top0 = tl0 + (tr0 - tl0) * lx;
                const float bot0 = bl0 + (br0 - bl0) * lx;
                const float top1 = tl1 + (tr1 - tl1) * lx;
                const float bot1 = bl1 + (br1 - bl1) * lx;
                v2[k] = (top0 + (bot0 - top0) * ly) * wm;
                v3[k] = (top1 + (bot1 - top1) * ly) * wm;
            }
        }

        float* dst = outc + (size_t)n * (NCH * CROP_HW) + j * 4;
        *reinterpret_cast<float4*>(dst)                = make_float4(v0[0], v0[1], v0[2], v0[3]);
        *reinterpret_cast<float4*>(dst + CROP_HW)      = make_float4(v1[0], v1[1], v1[2], v1[3]);
        *reinterpret_cast<float4*>(dst + 2 * CROP_HW)  = make_float4(v2[0], v2[1], v2[2], v2[3]);
        *reinterpret_cast<float4*>(dst + 3 * CROP_HW)  = make_float4(v3[0], v3[1], v3[2], v3[3]);
    }
}

extern "C" void kernel_launch(void* const* d_in, const int* in_sizes, int n_in,
                              void* d_out, int out_size, void* d_ws, size_t ws_size,
                              hipStream_t stream) {
    const float* image   = (const float*)d_in[0];
    const float* boxes   = (const float*)d_in[1];
    const int*   box_ind = (const int*)d_in[2];
    float* out = (float*)d_out;

    crop_resize_fused<<<dim3(NIMG * (NCH / 4)), dim3(512), 0, stream>>>(
        image, boxes, box_ind, out);
}

// Round 17
// 38.911 us; speedup vs baseline: 1.0128x; 1.0128x over previous
//
#include <hip/hip_runtime.h>
#include <hip/hip_fp16.h>

#define CROP_H 14
#define CROP_W 14
#define CROP_HW 196
#define CROP_HWQ 49          // quad units per box
#define IMG_H 100
#define IMG_W 100
#define PLANE 10000
#define NCH 256
#define NBOX 512
#define NIMG 8

// ---------------- fused single kernel: one block per (b, channel-pair) ----------
// Phase 1: ballot-scan builds per-image box list + per-box geometry scalars in LDS.
// Phase 2: stage the two channel planes as half2{c0,c1} (4 B/slot, conflict-free).
// Phase 3: hot loop with ZERO global loads: inline geometry (VALU) -> 4 LDS taps
//          serving two channels -> coalesced float4 stores.
__global__ __launch_bounds__(512, 4) void crop_resize_fused(
    const float* __restrict__ image,    // (8, 256, 100, 100)
    const float* __restrict__ boxes,    // (512, 4)
    const int*   __restrict__ box_ind,  // (512,)
    float* __restrict__ out)            // (512, 256, 14, 14)
{
    __shared__ __half2 s_du[PLANE];     // 40000 B: slot x = {c0[x], c1[x]}
    __shared__ float4  s_bgeo[NBOX];    // {ybase, ystep, xbase, xstep} per bucket slot
    __shared__ int     s_perm[NBOX];    // bucket slot -> box id n
    __shared__ int     s_eqw[8];        // per-wave bucket-membership counts

    const int blk  = blockIdx.x;
    const int b    = blk >> 7;          // image 0..7
    const int cp   = blk & 127;         // channel pair 0..127
    const int c0   = cp * 2;
    const int t    = threadIdx.x;
    const int lane = t & 63;
    const int wv   = t >> 6;            // 0..7

    // ---- phase 1a: membership ballot (t covers all 512 boxes) ----
    const int bn_t = box_ind[t];
    const bool mine = (bn_t == b);
    const unsigned long long eq = __ballot(mine);
    if (lane == 0) s_eqw[wv] = __popcll(eq);
    const int pre = __popcll(eq & ((lane == 0) ? 0ull : ((1ull << lane) - 1ull)));

    // ---- phase 2: stage two planes as channel-pair half2 ----
    const float* __restrict__ p0 = image + ((size_t)(b * NCH + c0)) * PLANE;
    const float4* __restrict__ p0g = reinterpret_cast<const float4*>(p0);
    const float4* __restrict__ p1g = reinterpret_cast<const float4*>(p0 + PLANE);

    for (int i = t; i < PLANE / 4; i += 512) {
        const float4 f0 = p0g[i];
        const float4 f1 = p1g[i];
        const int base = 4 * i;
        s_du[base + 0] = __floats2half2_rn(f0.x, f1.x);
        s_du[base + 1] = __floats2half2_rn(f0.y, f1.y);
        s_du[base + 2] = __floats2half2_rn(f0.z, f1.z);
        s_du[base + 3] = __floats2half2_rn(f0.w, f1.w);
    }
    __syncthreads();

    // ---- phase 1b: build perm + per-box geometry scalars ----
    int basecnt = 0, nb = 0;
    #pragma unroll
    for (int i = 0; i < 8; ++i) {
        const int cwv = s_eqw[i];
        if (i < wv) basecnt += cwv;
        nb += cwv;
    }
    if (mine) {
        const int r = basecnt + pre;
        s_perm[r] = t;
        const float4 bx = reinterpret_cast<const float4*>(boxes)[t];
        float4 g;
        g.x = bx.x * (float)(IMG_H - 1);                                  // ybase
        g.y = (bx.z - bx.x) * (float)(IMG_H - 1) / (float)(CROP_H - 1);   // ystep
        g.z = bx.y * (float)(IMG_W - 1);                                  // xbase
        g.w = (bx.w - bx.y) * (float)(IMG_W - 1) / (float)(CROP_W - 1);   // xstep
        s_bgeo[r] = g;
    }
    __syncthreads();

    const int totalq = nb * CROP_HWQ;
    float* __restrict__ outc = out + (size_t)c0 * CROP_HW;

    // ---- phase 3: pure LDS+VALU+store hot loop ----
    for (int q = t; q < totalq; q += 512) {
        const int bl = q / CROP_HWQ;            // magic-mul
        const int j  = q - bl * CROP_HWQ;       // quad index 0..48
        const int n  = s_perm[bl];              // broadcast-ish LDS read
        const float4 g = s_bgeo[bl];            // broadcast-ish LDS read

        float vals0[4], vals1[4];
        #pragma unroll
        for (int k = 0; k < 4; ++k) {
            const int hw = j * 4 + k;
            const int h  = hw / CROP_W;         // magic-mul
            const int w  = hw - h * CROP_W;

            const float in_y = g.x + (float)h * g.y;
            const float in_x = g.z + (float)w * g.w;

            const bool valid = (in_y >= 0.0f) & (in_y <= (float)(IMG_H - 1)) &
                               (in_x >= 0.0f) & (in_x <= (float)(IMG_W - 1));

            const float yc = fminf(fmaxf(in_y, 0.0f), (float)(IMG_H - 1));
            const float xc = fminf(fmaxf(in_x, 0.0f), (float)(IMG_W - 1));

            const float y0f = floorf(yc);
            const float x0f = floorf(xc);
            const float ly = yc - y0f;
            const float lx = xc - x0f;

            const int y0  = (int)y0f;
            const int x0  = (int)x0f;
            const int dx  = min(x0 + 1, IMG_W - 1) - x0;   // 0/1
            const int dyo = (min(y0 + 1, IMG_H - 1) - y0) * IMG_W;

            const int o = y0 * IMG_W + x0;

            const __half2 tl2 = s_du[o];
            const __half2 tr2 = s_du[o + dx];
            const __half2 bl2 = s_du[o + dyo];
            const __half2 br2 = s_du[o + dyo + dx];

            const float wm = valid ? 1.0f : 0.0f;

            const float tl0 = __low2float(tl2),  tl1 = __high2float(tl2);
            const float tr0 = __low2float(tr2),  tr1 = __high2float(tr2);
            const float bl0 = __low2float(bl2),  bl1 = __high2float(bl2);
            const float br0 = __low2float(br2),  br1 = __high2float(br2);

            const float top0 = tl0 + (tr0 - tl0) * lx;
            const float bot0 = bl0 + (br0 - bl0) * lx;
            const float top1 = tl1 + (tr1 - tl1) * lx;
            const float bot1 = bl1 + (br1 - bl1) * lx;

            vals0[k] = (top0 + (bot0 - top0) * ly) * wm;
            vals1[k] = (top1 + (bot1 - top1) * ly) * wm;
        }

        float* dst = outc + (size_t)n * (NCH * CROP_HW) + j * 4;
        *reinterpret_cast<float4*>(dst) =
            make_float4(vals0[0], vals0[1], vals0[2], vals0[3]);
        *reinterpret_cast<float4*>(dst + CROP_HW) =
            make_float4(vals1[0], vals1[1], vals1[2], vals1[3]);
    }
}

extern "C" void kernel_launch(void* const* d_in, const int* in_sizes, int n_in,
                              void* d_out, int out_size, void* d_ws, size_t ws_size,
                              hipStream_t stream) {
    const float* image   = (const float*)d_in[0];
    const float* boxes   = (const float*)d_in[1];
    const int*   box_ind = (const int*)d_in[2];
    float* out = (float*)d_out;

    crop_resize_fused<<<dim3(NIMG * (NCH / 2)), dim3(512), 0, stream>>>(
        image, boxes, box_ind, out);
}